// Round 9
// baseline (102.825 us; speedup 1.0000x reference)
//
#include <hip/hip_runtime.h>
#include <hip/hip_bf16.h>
#include <hip/hip_fp16.h>

typedef short s16x8 __attribute__((ext_vector_type(8)));
typedef float f32x4 __attribute__((ext_vector_type(4)));
typedef float f32x2 __attribute__((ext_vector_type(2)));
typedef unsigned int u32x4 __attribute__((ext_vector_type(4)));
typedef unsigned int u32x2 __attribute__((ext_vector_type(2)));

constexpr int Bb = 2, NQ = 13294, Hh = 8, HD = 32;
constexpr int Mrows = Bb * NQ; // 26588

__device__ inline short bf16_of(float f) {
  __hip_bfloat16 h = __float2bfloat16(f);
  return *reinterpret_cast<short*>(&h);
}

// Async global->LDS, 16B per lane. LDS dest must be linear: base + lane*16.
__device__ __forceinline__ void gload_lds16(const void* g, void* l) {
  __builtin_amdgcn_global_load_lds(
      (const __attribute__((address_space(1))) unsigned int*)g,
      (__attribute__((address_space(3))) unsigned int*)l, 16, 0, 0);
}

// One-time weight prep: WT[n][k] = bf16(W[k][n]) for Wv, {Wso|Waw} fused, Wo;
// bq = concat(bso, baw) fp32.
__global__ __launch_bounds__(256) void prep_k(
    const float* __restrict__ Wv, const float* __restrict__ Wso,
    const float* __restrict__ Waw, const float* __restrict__ Wo,
    const float* __restrict__ bso, const float* __restrict__ baw,
    short* __restrict__ WvT, short* __restrict__ WqT, short* __restrict__ WoT,
    float* __restrict__ bq)
{
  const int id = blockIdx.x * 256 + threadIdx.x;
  if (id < 384) bq[id] = id < 256 ? bso[id] : baw[id - 256];
  if (id < 65536) {
    int n = id >> 8, k = id & 255;
    WvT[id] = bf16_of(Wv[k * 256 + n]);
  } else if (id < 163840) {
    int t = id - 65536, n = t >> 8, k = t & 255;
    WqT[t] = bf16_of(n < 256 ? Wso[k * 256 + n] : Waw[k * 128 + (n - 256)]);
  } else {
    int t = id - 163840, n = t >> 8, k = t & 255;
    WoT[t] = bf16_of(Wo[k * 256 + n]);
  }
}

// m97-style GEMM: 128x128 tile, 4 waves (2x2) of 64x64 (4x4 frags).
// LDS [128][32] bf16, linear (full-coverage b128 reads are bank-uniform).
// B always staged via global_load_lds from prepped bf16 WT[n][k].
// A: MODE 3 -> global_load_lds (bf16); MODE 0/1 -> fp32 load + cvt + ds_write.
// Grid = 208 row-panels x NT col-tiles, XCD-swizzled (208 = 8 x 26).
// MODE 0: scatter vproj[B][H][NQ][HD] (NT=2); MODE 1: offaw[row*384+col]
// (NT=3, WqT fused [384][256]); MODE 3: fp32 out[row*256+col] (NT=2).
template<int MODE>
__device__ __forceinline__ void gemm_body(
    const void* __restrict__ Araw, const short* __restrict__ WT,
    const float* __restrict__ bias, void* __restrict__ outraw,
    int wg, short (* __restrict__ As)[32], short (* __restrict__ Bs)[32])
{
  constexpr int NT = (MODE == 1) ? 3 : 2;
  const int xcd = wg & 7, local = wg >> 3;
  const int row0 = (xcd * 26 + local / NT) * 128;
  const int col0 = (local % NT) * 128;
  const int tid = threadIdx.x, lane = tid & 63, wave = tid >> 6;
  const int wr = (wave >> 1) * 64, wc = (wave & 1) * 64;
  const int fr = lane & 15, kg = lane >> 4;
  const int srow = tid >> 2, sslot = tid & 3;   // staging: 64 rows x 4 slots/round
  f32x4 acc[4][4] = {};

  for (int kt = 0; kt < 256; kt += 32) {
#pragma unroll
    for (int p = 0; p < 2; p++) {
      const short* gb = WT + (size_t)(col0 + p * 64 + srow) * 256 + kt + sslot * 8;
      gload_lds16(gb, (short*)Bs + (p * 64 + srow) * 32 + sslot * 8);
    }
    if constexpr (MODE == 3) {
#pragma unroll
      for (int p = 0; p < 2; p++) {
        int r = min(row0 + p * 64 + srow, Mrows - 1);
        const short* ga = (const short*)Araw + (size_t)r * 256 + kt + sslot * 8;
        gload_lds16(ga, (short*)As + (p * 64 + srow) * 32 + sslot * 8);
      }
    } else {
      const float* A = (const float*)Araw;
#pragma unroll
      for (int p = 0; p < 2; p++) {
        int r = min(row0 + p * 64 + srow, Mrows - 1);
        f32x4 x0 = *(const f32x4*)(A + (size_t)r * 256 + kt + sslot * 8);
        f32x4 x1 = *(const f32x4*)(A + (size_t)r * 256 + kt + sslot * 8 + 4);
        s16x8 v;
#pragma unroll
        for (int i = 0; i < 4; i++) { v[i] = bf16_of(x0[i]); v[4 + i] = bf16_of(x1[i]); }
        *(s16x8*)((short*)As + (p * 64 + srow) * 32 + sslot * 8) = v;
      }
    }
    __syncthreads();   // compiler drains vmcnt+lgkmcnt here

    s16x8 af[4], bf[4];
#pragma unroll
    for (int m = 0; m < 4; m++) af[m] = *(const s16x8*)((const short*)As + (wr + m * 16 + fr) * 32 + kg * 8);
#pragma unroll
    for (int n = 0; n < 4; n++) bf[n] = *(const s16x8*)((const short*)Bs + (wc + n * 16 + fr) * 32 + kg * 8);
#pragma unroll
    for (int m = 0; m < 4; m++)
#pragma unroll
      for (int n = 0; n < 4; n++)
        acc[m][n] = __builtin_amdgcn_mfma_f32_16x16x32_bf16(af[m], bf[n], acc[m][n], 0, 0, 0);
    __syncthreads();
  }

  // D mapping (verified): col = fr (B-side), row-in-frag = kg*4 + r (A-side)
#pragma unroll
  for (int n = 0; n < 4; n++) {
    const int colL = col0 + wc + n * 16 + fr;
    const float bvf = bias[colL];
#pragma unroll
    for (int m = 0; m < 4; m++) {
#pragma unroll
      for (int r = 0; r < 4; r++) {
        const int rowL = row0 + wr + m * 16 + kg * 4 + r;
        if (rowL < Mrows) {
          float v = acc[m][n][r] + bvf;
          if constexpr (MODE == 0) {
            int b = rowL >= NQ, nn = rowL - b * NQ;
            int h = colL >> 5, c = colL & 31;
            ((__hip_bfloat16*)outraw)[(((size_t)b * Hh + h) * NQ + nn) * HD + c] = __float2bfloat16(v);
          } else if constexpr (MODE == 1) {
            ((__hip_bfloat16*)outraw)[(size_t)rowL * 384 + colL] = __float2bfloat16(v);
          } else {
            ((float*)outraw)[(size_t)rowL * 256 + colL] = v;
          }
        }
      }
    }
  }
}

// Fused value-proj (416 blocks) + query-proj (624 blocks).
__global__ __launch_bounds__(256) void gemm01_k(
    const float* __restrict__ value, const float* __restrict__ query,
    const short* __restrict__ WvT, const short* __restrict__ WqT,
    const float* __restrict__ bv, const float* __restrict__ bq,
    __hip_bfloat16* __restrict__ vproj, __hip_bfloat16* __restrict__ offaw)
{
  __shared__ short As[128][32];
  __shared__ short Bs[128][32];
  const int wg = blockIdx.x;
  if (wg < 416) gemm_body<0>(value, WvT, bv, vproj, wg, As, Bs);
  else          gemm_body<1>(query, WqT, bq, offaw, wg - 416, As, Bs);
}

__global__ __launch_bounds__(256) void gemm3_k(
    const short* __restrict__ interm, const short* __restrict__ WoT,
    const float* __restrict__ bo, float* __restrict__ out)
{
  __shared__ short As[128][32];
  __shared__ short Bs[128][32];
  gemm_body<3>(interm, WoT, bo, out, blockIdx.x, As, Bs);
}

// XCD-local, reduce-free sampler at full occupancy.
// Block = one (b,h) plane x 64 queries; plane = blockIdx&15 -> each XCD's L2
// sees ~2 planes (1.7MB) of vproj. Descriptor = 8B {byte_base<<6, half2(w0,w1)}
// -> LDS 16.6KB; launch_bounds(256,8) caps VGPR <=64 -> 8 blocks/CU (100%).
// Phase B: wave = [16 queries][4 ch-slices]; lane serially accumulates all 64
// gathers for its own 8 channels -> no cross-lane reduce.
__global__ __launch_bounds__(256, 8) void sample_k(
    const __hip_bfloat16* __restrict__ vproj,
    const __hip_bfloat16* __restrict__ offaw,
    const float* __restrict__ refp,
    __hip_bfloat16* __restrict__ interm)
{
  __shared__ u32x2 dpk[16][2][65];   // 16,640 B: [lp][yi][ql]
  const int plane = blockIdx.x & 15;
  const int chunk = blockIdx.x >> 4;
  const int b = plane >> 3, h = plane & 7;
  const int q0 = chunk * 64;
  const int tid = threadIdx.x;
  const int dims[4]   = {100, 50, 25, 13};
  const int starts[4] = {0, 10000, 12500, 13125};

#pragma unroll
  for (int it = 0; it < 4; it++) {
    const int task = it * 256 + tid;
    const int ql = task >> 4, lp = task & 15;
    const int l = lp >> 2;
    const int lw = dims[l];
    int q = q0 + ql; if (q >= NQ) q = NQ - 1;   // clamped read; store guarded later
    const size_t row = (size_t)b * NQ + q;
    unsigned int oxy = *(const unsigned int*)((const unsigned short*)offaw + row * 384 + h * 32 + lp * 2);
    float offx = __uint_as_float(oxy << 16);
    float offy = __uint_as_float(oxy & 0xffff0000u);
    float logit = __bfloat162float(offaw[row * 384 + 256 + h * 16 + lp]);
    float2 rp = *(const float2*)(refp + (row * 4 + l) * 2);
    float gx = rp.x * (float)lw + offx - 0.5f;
    float gy = rp.y * (float)lw + offy - 0.5f;
    float mx = logit;
#pragma unroll
    for (int d = 1; d < 16; d <<= 1) mx = fmaxf(mx, __shfl_xor(mx, d));
    float e = __expf(logit - mx);
    float ssum = e;
#pragma unroll
    for (int d = 1; d < 16; d <<= 1) ssum += __shfl_xor(ssum, d);
    float aw = e / ssum;

    float xf = floorf(gx), yf = floorf(gy);
    int x0 = (int)xf, y0 = (int)yf;
    float wx = gx - xf, wy = gy - yf;
    int bx = min(max(x0, 0), lw - 2);
    bool lxv = (x0 >= 0) & (x0 < lw);
    bool rxv = (x0 + 1 >= 0) & (x0 + 1 < lw);
    float wl = 1.f - wx, wr = wx;
    float ws0 = (lxv && x0 == bx     ? wl : 0.f) + (rxv && x0 + 1 == bx     ? wr : 0.f);
    float ws1 = (lxv && x0 == bx + 1 ? wl : 0.f) + (rxv && x0 + 1 == bx + 1 ? wr : 0.f);
    const int pbase = (b * Hh + h) * NQ + starts[l];
#pragma unroll
    for (int yi = 0; yi < 2; yi++) {
      int yc = y0 + yi;
      bool yv = (yc >= 0) & (yc < lw);
      int ycl = min(max(yc, 0), lw - 1);
      float wyt = (yi ? wy : 1.f - wy) * aw * (yv ? 1.f : 0.f);
      __half h0 = __float2half(ws0 * wyt);
      __half h1 = __float2half(ws1 * wyt);
      u32x2 pk;
      pk[0] = (unsigned int)((pbase + ycl * lw + bx) << 6);   // pre-shifted byte base
      pk[1] = (unsigned int)(*(unsigned short*)&h0)
            | ((unsigned int)(*(unsigned short*)&h1) << 16);
      dpk[lp][yi][ql] = pk;
    }
  }
  __syncthreads();

  const int wv = tid >> 6, lane = tid & 63;
  const int qsub = lane >> 2, c = lane & 3;
  const int ql = wv * 16 + qsub;
  const char* vpc = (const char*)vproj + c * 16;
  f32x2 a2[4] = {};
#pragma unroll 4
  for (int lp = 0; lp < 16; lp++) {
#pragma unroll
    for (int yi = 0; yi < 2; yi++) {
      const u32x2 d = dpk[lp][yi][ql];
      const char* p = vpc + d[0];
      const u32x4 u0 = *(const u32x4*)p;
      const u32x4 u1 = *(const u32x4*)(p + 64);
      unsigned short hw0 = (unsigned short)(d[1] & 0xffffu);
      unsigned short hw1 = (unsigned short)(d[1] >> 16);
      const float w0 = __half2float(*(const __half*)&hw0);
      const float w1 = __half2float(*(const __half*)&hw1);
      const f32x2 wb0 = {w0, w0};
      const f32x2 wb1 = {w1, w1};
#pragma unroll
      for (int j = 0; j < 4; j++) {
        f32x2 v0 = { __uint_as_float(u0[j] << 16), __uint_as_float(u0[j] & 0xffff0000u) };
        f32x2 v1 = { __uint_as_float(u1[j] << 16), __uint_as_float(u1[j] & 0xffff0000u) };
        a2[j] += v0 * wb0;
        a2[j] += v1 * wb1;
      }
    }
  }
  const int q = q0 + ql;
  if (q < NQ) {
    unsigned int up[4];
#pragma unroll
    for (int j = 0; j < 4; j++) {
      unsigned int b0 = (unsigned int)(unsigned short)bf16_of(a2[j][0]);
      unsigned int b1 = (unsigned int)(unsigned short)bf16_of(a2[j][1]);
      up[j] = (b1 << 16) | b0;
    }
    u32x4 pk = { up[0], up[1], up[2], up[3] };
    *(u32x4*)((unsigned short*)interm + ((size_t)b * NQ + q) * 256 + h * 32 + c * 8) = pk;
  }
}

extern "C" void kernel_launch(void* const* d_in, const int* in_sizes, int n_in,
                              void* d_out, int out_size, void* d_ws, size_t ws_size,
                              hipStream_t stream)
{
  const float* query = (const float*)d_in[0];
  const float* refp  = (const float*)d_in[1];
  const float* value = (const float*)d_in[2];
  // d_in[3] = spatial_shapes (static, hardcoded)
  const float* Wso = (const float*)d_in[4];
  const float* bso = (const float*)d_in[5];
  const float* Waw = (const float*)d_in[6];
  const float* baw = (const float*)d_in[7];
  const float* Wv  = (const float*)d_in[8];
  const float* bv  = (const float*)d_in[9];
  const float* Wo  = (const float*)d_in[10];
  const float* bo  = (const float*)d_in[11];

  char* ws = (char*)d_ws;
  __hip_bfloat16* vproj  = (__hip_bfloat16*)ws;                 // 13,613,056 B
  __hip_bfloat16* offaw  = (__hip_bfloat16*)(ws + 13613056);    // 20,419,584 B
  __hip_bfloat16* interm = (__hip_bfloat16*)(ws + 34032640);    // 13,613,056 B
  short* WvT = (short*)(ws + 47645696);                         //    131,072 B
  short* WqT = (short*)(ws + 47776768);                         //    196,608 B
  short* WoT = (short*)(ws + 47973376);                         //    131,072 B
  float* bq  = (float*)(ws + 48104448);                         //      1,536 B
  float* out = (float*)d_out;

  dim3 blk(256);
  prep_k<<<dim3(896), blk, 0, stream>>>(Wv, Wso, Waw, Wo, bso, baw, WvT, WqT, WoT, bq);
  gemm01_k<<<dim3(416 + 624), blk, 0, stream>>>(value, query, WvT, WqT, bv, bq, vproj, offaw);
  sample_k<<<dim3(16 * 208), blk, 0, stream>>>(vproj, offaw, refp, interm);
  gemm3_k<<<dim3(416), blk, 0, stream>>>((const short*)interm, WoT, bo, out);
}

// Round 10
// 99.442 us; speedup vs baseline: 1.0340x; 1.0340x over previous
//
#include <hip/hip_runtime.h>
#include <hip/hip_bf16.h>
#include <hip/hip_fp16.h>

typedef short s16x8 __attribute__((ext_vector_type(8)));
typedef float f32x4 __attribute__((ext_vector_type(4)));
typedef float f32x2 __attribute__((ext_vector_type(2)));
typedef unsigned int u32x4 __attribute__((ext_vector_type(4)));
typedef unsigned int u32x2 __attribute__((ext_vector_type(2)));

constexpr int Bb = 2, NQ = 13294, Hh = 8, HD = 32;
constexpr int Mrows = Bb * NQ; // 26588

__device__ inline short bf16_of(float f) {
  __hip_bfloat16 h = __float2bfloat16(f);
  return *reinterpret_cast<short*>(&h);
}

// One-time weight prep: WT[n][k] = bf16(W[k][n]) for Wv, {Wso|Waw} fused, Wo;
// bq = concat(bso, baw) fp32.
__global__ __launch_bounds__(256) void prep_k(
    const float* __restrict__ Wv, const float* __restrict__ Wso,
    const float* __restrict__ Waw, const float* __restrict__ Wo,
    const float* __restrict__ bso, const float* __restrict__ baw,
    short* __restrict__ WvT, short* __restrict__ WqT, short* __restrict__ WoT,
    float* __restrict__ bq)
{
  const int id = blockIdx.x * 256 + threadIdx.x;
  if (id < 384) bq[id] = id < 256 ? bso[id] : baw[id - 256];
  if (id < 65536) {
    int n = id >> 8, k = id & 255;
    WvT[id] = bf16_of(Wv[k * 256 + n]);
  } else if (id < 163840) {
    int t = id - 65536, n = t >> 8, k = t & 255;
    WqT[t] = bf16_of(n < 256 ? Wso[k * 256 + n] : Waw[k * 128 + (n - 256)]);
  } else {
    int t = id - 163840, n = t >> 8, k = t & 255;
    WoT[t] = bf16_of(Wo[k * 256 + n]);
  }
}

// Round-8 GEMM (best measured): pipelined 128x64 tile, double-buffered LDS,
// register prefetch of tile t+1 before MFMA of t, ONE barrier per K-step.
// 208 row-panels = 8 XCDs x 26; xcd = wg&7 owns 26 contiguous panels x NT
// col-tiles (col-fast) so the A panel is HBM-fetched once per XCD.
// MODE 0: A fp32 -> bf16 scatter vproj[B][H][NQ][HD] (NT=4)
// MODE 1: A fp32 -> bf16 offaw[row*384+col], fused Wso|Waw (NT=6)
// MODE 3: A bf16 -> fp32 out[row*256+col] (NT=4)
template<int MODE>
__device__ __forceinline__ void gemm_body(
    const void* __restrict__ Araw, const short* __restrict__ WT,
    const float* __restrict__ bias, void* __restrict__ outraw,
    int wg, short (* __restrict__ As)[128][40], short (* __restrict__ Bs)[64][40])
{
  constexpr int NT = (MODE == 1) ? 6 : 4;
  const int xcd = wg & 7, local = wg >> 3;
  const int row0 = (xcd * 26 + local / NT) * 128;
  const int col0 = (local % NT) * 64;
  const int tid = threadIdx.x, lane = tid & 63, wave = tid >> 6;

  f32x4 acc[2][4] = {};

  int arow[2], aq[2], ga[2];
#pragma unroll
  for (int it = 0; it < 2; it++) {
    int task = it * 256 + tid;
    arow[it] = task >> 2; aq[it] = task & 3;
    ga[it] = min(row0 + arow[it], Mrows - 1);
  }
  const int bcol = tid >> 2, bqd = tid & 3;

  f32x4 a0[2], a1[2]; s16x8 abf[2]; s16x8 breg;

  auto load_tile = [&](int kt) {
#pragma unroll
    for (int it = 0; it < 2; it++) {
      if constexpr (MODE == 3) {
        abf[it] = *(const s16x8*)((const short*)Araw + (size_t)ga[it] * 256 + kt + aq[it] * 8);
      } else {
        const float* A = (const float*)Araw;
        a0[it] = *(const f32x4*)(A + (size_t)ga[it] * 256 + kt + aq[it] * 8);
        a1[it] = *(const f32x4*)(A + (size_t)ga[it] * 256 + kt + aq[it] * 8 + 4);
      }
    }
    breg = *(const s16x8*)(WT + (size_t)(col0 + bcol) * 256 + kt + bqd * 8);
  };

  auto write_tile = [&](int buf) {
#pragma unroll
    for (int it = 0; it < 2; it++) {
      s16x8 av;
      if constexpr (MODE == 3) { av = abf[it]; }
      else {
#pragma unroll
        for (int i = 0; i < 4; i++) { av[i] = bf16_of(a0[it][i]); av[4 + i] = bf16_of(a1[it][i]); }
      }
      *(s16x8*)(&As[buf][arow[it]][aq[it] * 8]) = av;
    }
    *(s16x8*)(&Bs[buf][bcol][bqd * 8]) = breg;
  };

  load_tile(0);
  const int fr = lane & 15, kg = lane >> 4;
#pragma unroll
  for (int t = 0; t < 8; t++) {
    const int buf = t & 1;
    write_tile(buf);
    __syncthreads();
    if (t < 7) load_tile((t + 1) * 32);   // in flight across the MFMA below
    s16x8 bfr[4], afr[2];
#pragma unroll
    for (int n = 0; n < 4; n++) bfr[n] = *(const s16x8*)(&Bs[buf][n * 16 + fr][kg * 8]);
#pragma unroll
    for (int m = 0; m < 2; m++) afr[m] = *(const s16x8*)(&As[buf][wave * 32 + m * 16 + fr][kg * 8]);
#pragma unroll
    for (int m = 0; m < 2; m++)
#pragma unroll
      for (int n = 0; n < 4; n++)
        acc[m][n] = __builtin_amdgcn_mfma_f32_16x16x32_bf16(afr[m], bfr[n], acc[m][n], 0, 0, 0);
  }

  // D mapping (verified): col = lane&15, row-in-frag = kg*4 + reg
#pragma unroll
  for (int n = 0; n < 4; n++) {
    const int colL = col0 + n * 16 + fr;
    const float bvf = bias[colL];
#pragma unroll
    for (int m = 0; m < 2; m++) {
#pragma unroll
      for (int r = 0; r < 4; r++) {
        const int rowL = row0 + wave * 32 + m * 16 + kg * 4 + r;
        if (rowL < Mrows) {
          float v = acc[m][n][r] + bvf;
          if constexpr (MODE == 0) {
            int b = rowL >= NQ, nn = rowL - b * NQ;
            int h = colL >> 5, c = colL & 31;
            ((__hip_bfloat16*)outraw)[(((size_t)b * Hh + h) * NQ + nn) * HD + c] = __float2bfloat16(v);
          } else if constexpr (MODE == 1) {
            ((__hip_bfloat16*)outraw)[(size_t)rowL * 384 + colL] = __float2bfloat16(v);
          } else {
            ((float*)outraw)[(size_t)rowL * 256 + colL] = v;
          }
        }
      }
    }
  }
}

// Fused value-proj + query-proj (independent GEMMs, one launch).
__global__ __launch_bounds__(256) void gemm01_k(
    const float* __restrict__ value, const float* __restrict__ query,
    const short* __restrict__ WvT, const short* __restrict__ WqT,
    const float* __restrict__ bv, const float* __restrict__ bq,
    __hip_bfloat16* __restrict__ vproj, __hip_bfloat16* __restrict__ offaw)
{
  __shared__ short As[2][128][40];
  __shared__ short Bs[2][64][40];
  const int wg = blockIdx.x;
  if (wg < 832) gemm_body<0>(value, WvT, bv, vproj, wg, As, Bs);
  else          gemm_body<1>(query, WqT, bq, offaw, wg - 832, As, Bs);
}

__global__ __launch_bounds__(256) void gemm3_k(
    const short* __restrict__ interm, const short* __restrict__ WoT,
    const float* __restrict__ bo, float* __restrict__ out)
{
  __shared__ short As[2][128][40];
  __shared__ short Bs[2][64][40];
  gemm_body<3>(interm, WoT, bo, out, blockIdx.x, As, Bs);
}

// XCD-local, reduce-free sampler — tail-free grid.
// Grid = 16 planes x 104 = 1664 blocks (<= 2048 resident -> single dispatch
// round, no ragged tail). Each block processes 2 sequential 64-query chunks,
// reusing the same 16.6KB LDS. plane = blockIdx&15 keeps each XCD's gathers
// confined to ~2 (b,h) planes (1.7MB of vproj, L2-resident).
// Phase A: 1024 (ql,lp) descriptor tasks, fused 16-wide softmax; descriptor =
// 8B {byte_base, half2(w0,w1)}. Phase B: wave = [16 queries][4 ch-slices];
// lane serially accumulates all 64 gathers for its own 8 channels.
__global__ __launch_bounds__(256, 8) void sample_k(
    const __hip_bfloat16* __restrict__ vproj,
    const __hip_bfloat16* __restrict__ offaw,
    const float* __restrict__ refp,
    __hip_bfloat16* __restrict__ interm)
{
  __shared__ u32x2 dpk[16][2][65];   // 16,640 B: [lp][yi][ql]
  const int plane = blockIdx.x & 15;
  const int pair  = blockIdx.x >> 4;
  const int b = plane >> 3, h = plane & 7;
  const int tid = threadIdx.x;
  const int dims[4]   = {100, 50, 25, 13};
  const int starts[4] = {0, 10000, 12500, 13125};

  for (int cix = 0; cix < 2; cix++) {
    const int q0 = (pair * 2 + cix) * 64;

#pragma unroll
    for (int it = 0; it < 4; it++) {
      const int task = it * 256 + tid;
      const int ql = task >> 4, lp = task & 15;
      const int l = lp >> 2;
      const int lw = dims[l];
      int q = q0 + ql; if (q >= NQ) q = NQ - 1;   // clamped read; store guarded later
      const size_t row = (size_t)b * NQ + q;
      unsigned int oxy = *(const unsigned int*)((const unsigned short*)offaw + row * 384 + h * 32 + lp * 2);
      float offx = __uint_as_float(oxy << 16);
      float offy = __uint_as_float(oxy & 0xffff0000u);
      float logit = __bfloat162float(offaw[row * 384 + 256 + h * 16 + lp]);
      float2 rp = *(const float2*)(refp + (row * 4 + l) * 2);
      float gx = rp.x * (float)lw + offx - 0.5f;
      float gy = rp.y * (float)lw + offy - 0.5f;
      float mx = logit;
#pragma unroll
      for (int d = 1; d < 16; d <<= 1) mx = fmaxf(mx, __shfl_xor(mx, d));
      float e = __expf(logit - mx);
      float ssum = e;
#pragma unroll
      for (int d = 1; d < 16; d <<= 1) ssum += __shfl_xor(ssum, d);
      float aw = e / ssum;

      float xf = floorf(gx), yf = floorf(gy);
      int x0 = (int)xf, y0 = (int)yf;
      float wx = gx - xf, wy = gy - yf;
      int bx = min(max(x0, 0), lw - 2);
      bool lxv = (x0 >= 0) & (x0 < lw);
      bool rxv = (x0 + 1 >= 0) & (x0 + 1 < lw);
      float wl = 1.f - wx, wr = wx;
      float ws0 = (lxv && x0 == bx     ? wl : 0.f) + (rxv && x0 + 1 == bx     ? wr : 0.f);
      float ws1 = (lxv && x0 == bx + 1 ? wl : 0.f) + (rxv && x0 + 1 == bx + 1 ? wr : 0.f);
      const int pbase = (b * Hh + h) * NQ + starts[l];
#pragma unroll
      for (int yi = 0; yi < 2; yi++) {
        int yc = y0 + yi;
        bool yv = (yc >= 0) & (yc < lw);
        int ycl = min(max(yc, 0), lw - 1);
        float wyt = (yi ? wy : 1.f - wy) * aw * (yv ? 1.f : 0.f);
        __half h0 = __float2half(ws0 * wyt);
        __half h1 = __float2half(ws1 * wyt);
        u32x2 pk;
        pk[0] = (unsigned int)((pbase + ycl * lw + bx) << 6);   // pre-shifted byte base
        pk[1] = (unsigned int)(*(unsigned short*)&h0)
              | ((unsigned int)(*(unsigned short*)&h1) << 16);
        dpk[lp][yi][ql] = pk;
      }
    }
    __syncthreads();

    const int wv = tid >> 6, lane = tid & 63;
    const int qsub = lane >> 2, c = lane & 3;
    const int ql = wv * 16 + qsub;
    const char* vpc = (const char*)vproj + c * 16;
    f32x2 a2[4] = {};
#pragma unroll 4
    for (int lp = 0; lp < 16; lp++) {
#pragma unroll
      for (int yi = 0; yi < 2; yi++) {
        const u32x2 d = dpk[lp][yi][ql];
        const char* p = vpc + d[0];
        const u32x4 u0 = *(const u32x4*)p;
        const u32x4 u1 = *(const u32x4*)(p + 64);
        unsigned short hw0 = (unsigned short)(d[1] & 0xffffu);
        unsigned short hw1 = (unsigned short)(d[1] >> 16);
        const float w0 = __half2float(*(const __half*)&hw0);
        const float w1 = __half2float(*(const __half*)&hw1);
        const f32x2 wb0 = {w0, w0};
        const f32x2 wb1 = {w1, w1};
#pragma unroll
        for (int j = 0; j < 4; j++) {
          f32x2 v0 = { __uint_as_float(u0[j] << 16), __uint_as_float(u0[j] & 0xffff0000u) };
          f32x2 v1 = { __uint_as_float(u1[j] << 16), __uint_as_float(u1[j] & 0xffff0000u) };
          a2[j] += v0 * wb0;
          a2[j] += v1 * wb1;
        }
      }
    }
    const int q = q0 + ql;
    if (q < NQ) {
      unsigned int up[4];
#pragma unroll
      for (int j = 0; j < 4; j++) {
        unsigned int b0 = (unsigned int)(unsigned short)bf16_of(a2[j][0]);
        unsigned int b1 = (unsigned int)(unsigned short)bf16_of(a2[j][1]);
        up[j] = (b1 << 16) | b0;
      }
      u32x4 pk = { up[0], up[1], up[2], up[3] };
      *(u32x4*)((unsigned short*)interm + ((size_t)b * NQ + q) * 256 + h * 32 + c * 8) = pk;
    }
    __syncthreads();   // protect LDS before next chunk's phase A
  }
}

extern "C" void kernel_launch(void* const* d_in, const int* in_sizes, int n_in,
                              void* d_out, int out_size, void* d_ws, size_t ws_size,
                              hipStream_t stream)
{
  const float* query = (const float*)d_in[0];
  const float* refp  = (const float*)d_in[1];
  const float* value = (const float*)d_in[2];
  // d_in[3] = spatial_shapes (static, hardcoded)
  const float* Wso = (const float*)d_in[4];
  const float* bso = (const float*)d_in[5];
  const float* Waw = (const float*)d_in[6];
  const float* baw = (const float*)d_in[7];
  const float* Wv  = (const float*)d_in[8];
  const float* bv  = (const float*)d_in[9];
  const float* Wo  = (const float*)d_in[10];
  const float* bo  = (const float*)d_in[11];

  char* ws = (char*)d_ws;
  __hip_bfloat16* vproj  = (__hip_bfloat16*)ws;                 // 13,613,056 B
  __hip_bfloat16* offaw  = (__hip_bfloat16*)(ws + 13613056);    // 20,419,584 B
  __hip_bfloat16* interm = (__hip_bfloat16*)(ws + 34032640);    // 13,613,056 B
  short* WvT = (short*)(ws + 47645696);                         //    131,072 B
  short* WqT = (short*)(ws + 47776768);                         //    196,608 B
  short* WoT = (short*)(ws + 47973376);                         //    131,072 B
  float* bq  = (float*)(ws + 48104448);                         //      1,536 B
  float* out = (float*)d_out;

  dim3 blk(256);
  prep_k<<<dim3(896), blk, 0, stream>>>(Wv, Wso, Waw, Wo, bso, baw, WvT, WqT, WoT, bq);
  gemm01_k<<<dim3(832 + 1248), blk, 0, stream>>>(value, query, WvT, WqT, bv, bq, vproj, offaw);
  sample_k<<<dim3(16 * 104), blk, 0, stream>>>(vproj, offaw, refp, interm);
  gemm3_k<<<dim3(832), blk, 0, stream>>>((const short*)interm, WoT, bo, out);
}

// Round 11
// 97.903 us; speedup vs baseline: 1.0503x; 1.0157x over previous
//
#include <hip/hip_runtime.h>
#include <hip/hip_bf16.h>
#include <hip/hip_fp16.h>

typedef short s16x8 __attribute__((ext_vector_type(8)));
typedef float f32x4 __attribute__((ext_vector_type(4)));
typedef float f32x2 __attribute__((ext_vector_type(2)));
typedef unsigned int u32x4 __attribute__((ext_vector_type(4)));
typedef unsigned int u32x2 __attribute__((ext_vector_type(2)));

constexpr int Bb = 2, NQ = 13294, Hh = 8, HD = 32;
constexpr int Mrows = Bb * NQ; // 26588

__device__ inline short bf16_of(float f) {
  __hip_bfloat16 h = __float2bfloat16(f);
  return *reinterpret_cast<short*>(&h);
}

// One-time weight prep via LDS-tiled transpose (coalesced read AND write):
// WT[n][k] = bf16(W[k][n]) for Wv, {Wso|Waw} fused (384 rows), Wo.
// 64x64 tiles; 56 tiles + 1 bias block.
__global__ __launch_bounds__(256) void prep_k(
    const float* __restrict__ Wv, const float* __restrict__ Wso,
    const float* __restrict__ Waw, const float* __restrict__ Wo,
    const float* __restrict__ bso, const float* __restrict__ baw,
    short* __restrict__ WvT, short* __restrict__ WqT, short* __restrict__ WoT,
    float* __restrict__ bq)
{
  __shared__ short lds[64][65];
  const int tid = threadIdx.x;
  int t = blockIdx.x;
  if (t == 56) {   // bias concat
#pragma unroll
    for (int i = 0; i < 2; i++) {
      int id = i * 256 + tid;
      if (id < 384) bq[id] = id < 256 ? bso[id] : baw[id - 256];
    }
    return;
  }
  const float* src; short* dst; int ldS, n0, k0, drow0;
  if (t < 16)      { src = Wv;  dst = WvT; ldS = 256; n0 = (t >> 2) * 64;        k0 = (t & 3) * 64; drow0 = n0; }
  else if (t < 32) { t -= 16; src = Wso; dst = WqT; ldS = 256; n0 = (t >> 2) * 64; k0 = (t & 3) * 64; drow0 = n0; }
  else if (t < 40) { t -= 32; src = Waw; dst = WqT; ldS = 128; n0 = (t >> 2) * 64; k0 = (t & 3) * 64; drow0 = 256 + n0; }
  else             { t -= 40; src = Wo;  dst = WoT; ldS = 256; n0 = (t >> 2) * 64; k0 = (t & 3) * 64; drow0 = n0; }

#pragma unroll
  for (int i = 0; i < 16; i++) {
    int idx = i * 256 + tid;
    int kk = idx >> 6, nn = idx & 63;          // consecutive tid -> consecutive nn (coalesced read)
    lds[nn][kk] = bf16_of(src[(size_t)(k0 + kk) * ldS + n0 + nn]);
  }
  __syncthreads();
#pragma unroll
  for (int i = 0; i < 16; i++) {
    int idx = i * 256 + tid;
    int nn = idx >> 6, kk = idx & 63;          // consecutive tid -> consecutive kk (coalesced write)
    dst[(size_t)(drow0 + nn) * 256 + k0 + kk] = lds[nn][kk];
  }
}

// Round-8 GEMM (best measured): pipelined 128x64 tile, double-buffered LDS,
// register prefetch of tile t+1 before MFMA of t, ONE barrier per K-step.
// 208 row-panels = 8 XCDs x 26; xcd = wg&7 owns 26 contiguous panels x NT
// col-tiles (col-fast) so the A panel is HBM-fetched once per XCD.
// MODE 0: A fp32 -> FP16 scatter vproj[B][H][NQ][HD] (NT=4)
// MODE 1: A fp32 -> bf16 offaw[row*384+col], fused Wso|Waw (NT=6)
// MODE 3: A bf16 -> fp32 out[row*256+col] (NT=4)
template<int MODE>
__device__ __forceinline__ void gemm_body(
    const void* __restrict__ Araw, const short* __restrict__ WT,
    const float* __restrict__ bias, void* __restrict__ outraw,
    int wg, short (* __restrict__ As)[128][40], short (* __restrict__ Bs)[64][40])
{
  constexpr int NT = (MODE == 1) ? 6 : 4;
  const int xcd = wg & 7, local = wg >> 3;
  const int row0 = (xcd * 26 + local / NT) * 128;
  const int col0 = (local % NT) * 64;
  const int tid = threadIdx.x, lane = tid & 63, wave = tid >> 6;

  f32x4 acc[2][4] = {};

  int arow[2], aq[2], ga[2];
#pragma unroll
  for (int it = 0; it < 2; it++) {
    int task = it * 256 + tid;
    arow[it] = task >> 2; aq[it] = task & 3;
    ga[it] = min(row0 + arow[it], Mrows - 1);
  }
  const int bcol = tid >> 2, bqd = tid & 3;

  f32x4 a0[2], a1[2]; s16x8 abf[2]; s16x8 breg;

  auto load_tile = [&](int kt) {
#pragma unroll
    for (int it = 0; it < 2; it++) {
      if constexpr (MODE == 3) {
        abf[it] = *(const s16x8*)((const short*)Araw + (size_t)ga[it] * 256 + kt + aq[it] * 8);
      } else {
        const float* A = (const float*)Araw;
        a0[it] = *(const f32x4*)(A + (size_t)ga[it] * 256 + kt + aq[it] * 8);
        a1[it] = *(const f32x4*)(A + (size_t)ga[it] * 256 + kt + aq[it] * 8 + 4);
      }
    }
    breg = *(const s16x8*)(WT + (size_t)(col0 + bcol) * 256 + kt + bqd * 8);
  };

  auto write_tile = [&](int buf) {
#pragma unroll
    for (int it = 0; it < 2; it++) {
      s16x8 av;
      if constexpr (MODE == 3) { av = abf[it]; }
      else {
#pragma unroll
        for (int i = 0; i < 4; i++) { av[i] = bf16_of(a0[it][i]); av[4 + i] = bf16_of(a1[it][i]); }
      }
      *(s16x8*)(&As[buf][arow[it]][aq[it] * 8]) = av;
    }
    *(s16x8*)(&Bs[buf][bcol][bqd * 8]) = breg;
  };

  load_tile(0);
  const int fr = lane & 15, kg = lane >> 4;
#pragma unroll
  for (int t = 0; t < 8; t++) {
    const int buf = t & 1;
    write_tile(buf);
    __syncthreads();
    if (t < 7) load_tile((t + 1) * 32);   // in flight across the MFMA below
    s16x8 bfr[4], afr[2];
#pragma unroll
    for (int n = 0; n < 4; n++) bfr[n] = *(const s16x8*)(&Bs[buf][n * 16 + fr][kg * 8]);
#pragma unroll
    for (int m = 0; m < 2; m++) afr[m] = *(const s16x8*)(&As[buf][wave * 32 + m * 16 + fr][kg * 8]);
#pragma unroll
    for (int m = 0; m < 2; m++)
#pragma unroll
      for (int n = 0; n < 4; n++)
        acc[m][n] = __builtin_amdgcn_mfma_f32_16x16x32_bf16(afr[m], bfr[n], acc[m][n], 0, 0, 0);
  }

  // D mapping (verified): col = lane&15, row-in-frag = kg*4 + reg
#pragma unroll
  for (int n = 0; n < 4; n++) {
    const int colL = col0 + n * 16 + fr;
    const float bvf = bias[colL];
#pragma unroll
    for (int m = 0; m < 2; m++) {
#pragma unroll
      for (int r = 0; r < 4; r++) {
        const int rowL = row0 + wave * 32 + m * 16 + kg * 4 + r;
        if (rowL < Mrows) {
          float v = acc[m][n][r] + bvf;
          if constexpr (MODE == 0) {
            int b = rowL >= NQ, nn = rowL - b * NQ;
            int h = colL >> 5, c = colL & 31;
            ((__half*)outraw)[(((size_t)b * Hh + h) * NQ + nn) * HD + c] = __float2half(v);
          } else if constexpr (MODE == 1) {
            ((__hip_bfloat16*)outraw)[(size_t)rowL * 384 + colL] = __float2bfloat16(v);
          } else {
            ((float*)outraw)[(size_t)rowL * 256 + colL] = v;
          }
        }
      }
    }
  }
}

// Fused value-proj + query-proj (independent GEMMs, one launch).
__global__ __launch_bounds__(256) void gemm01_k(
    const float* __restrict__ value, const float* __restrict__ query,
    const short* __restrict__ WvT, const short* __restrict__ WqT,
    const float* __restrict__ bv, const float* __restrict__ bq,
    __half* __restrict__ vproj, __hip_bfloat16* __restrict__ offaw)
{
  __shared__ short As[2][128][40];
  __shared__ short Bs[2][64][40];
  const int wg = blockIdx.x;
  if (wg < 832) gemm_body<0>(value, WvT, bv, vproj, wg, As, Bs);
  else          gemm_body<1>(query, WqT, bq, offaw, wg - 832, As, Bs);
}

__global__ __launch_bounds__(256) void gemm3_k(
    const short* __restrict__ interm, const short* __restrict__ WoT,
    const float* __restrict__ bo, float* __restrict__ out)
{
  __shared__ short As[2][128][40];
  __shared__ short Bs[2][64][40];
  gemm_body<3>(interm, WoT, bo, out, blockIdx.x, As, Bs);
}

// XCD-local, reduce-free sampler (r9 grid) with fp16 packed-FMA accumulation.
// Block = one (b,h) plane x 64 queries; plane = blockIdx&15 -> each XCD's L2
// sees ~2 planes of vproj (fp16, 1.7MB). Descriptor = 8B {byte_base, half2}.
// Phase B: wave = [16 queries][4 ch-slices]; lane serially accumulates all 64
// gathers for its own 8 channels via __hfma2 (v_pk_fma_f16) — no unpack VALU.
// Two half2 accumulator sets (y0/y1 rows, <=32 terms each) summed in f32.
__global__ __launch_bounds__(256, 8) void sample_k(
    const __half* __restrict__ vproj,
    const __hip_bfloat16* __restrict__ offaw,
    const float* __restrict__ refp,
    __hip_bfloat16* __restrict__ interm)
{
  __shared__ u32x2 dpk[16][2][65];   // 16,640 B: [lp][yi][ql]
  const int plane = blockIdx.x & 15;
  const int chunk = blockIdx.x >> 4;
  const int b = plane >> 3, h = plane & 7;
  const int q0 = chunk * 64;
  const int tid = threadIdx.x;
  const int dims[4]   = {100, 50, 25, 13};
  const int starts[4] = {0, 10000, 12500, 13125};

#pragma unroll
  for (int it = 0; it < 4; it++) {
    const int task = it * 256 + tid;
    const int ql = task >> 4, lp = task & 15;
    const int l = lp >> 2;
    const int lw = dims[l];
    int q = q0 + ql; if (q >= NQ) q = NQ - 1;   // clamped read; store guarded later
    const size_t row = (size_t)b * NQ + q;
    unsigned int oxy = *(const unsigned int*)((const unsigned short*)offaw + row * 384 + h * 32 + lp * 2);
    float offx = __uint_as_float(oxy << 16);
    float offy = __uint_as_float(oxy & 0xffff0000u);
    float logit = __bfloat162float(offaw[row * 384 + 256 + h * 16 + lp]);
    float2 rp = *(const float2*)(refp + (row * 4 + l) * 2);
    float gx = rp.x * (float)lw + offx - 0.5f;
    float gy = rp.y * (float)lw + offy - 0.5f;
    float mx = logit;
#pragma unroll
    for (int d = 1; d < 16; d <<= 1) mx = fmaxf(mx, __shfl_xor(mx, d));
    float e = __expf(logit - mx);
    float ssum = e;
#pragma unroll
    for (int d = 1; d < 16; d <<= 1) ssum += __shfl_xor(ssum, d);
    float aw = e / ssum;

    float xf = floorf(gx), yf = floorf(gy);
    int x0 = (int)xf, y0 = (int)yf;
    float wx = gx - xf, wy = gy - yf;
    int bx = min(max(x0, 0), lw - 2);
    bool lxv = (x0 >= 0) & (x0 < lw);
    bool rxv = (x0 + 1 >= 0) & (x0 + 1 < lw);
    float wl = 1.f - wx, wr = wx;
    float ws0 = (lxv && x0 == bx     ? wl : 0.f) + (rxv && x0 + 1 == bx     ? wr : 0.f);
    float ws1 = (lxv && x0 == bx + 1 ? wl : 0.f) + (rxv && x0 + 1 == bx + 1 ? wr : 0.f);
    const int pbase = (b * Hh + h) * NQ + starts[l];
#pragma unroll
    for (int yi = 0; yi < 2; yi++) {
      int yc = y0 + yi;
      bool yv = (yc >= 0) & (yc < lw);
      int ycl = min(max(yc, 0), lw - 1);
      float wyt = (yi ? wy : 1.f - wy) * aw * (yv ? 1.f : 0.f);
      __half h0 = __float2half(ws0 * wyt);
      __half h1 = __float2half(ws1 * wyt);
      u32x2 pk;
      pk[0] = (unsigned int)((pbase + ycl * lw + bx) << 6);   // pre-shifted byte base
      pk[1] = (unsigned int)(*(unsigned short*)&h0)
            | ((unsigned int)(*(unsigned short*)&h1) << 16);
      dpk[lp][yi][ql] = pk;
    }
  }
  __syncthreads();

  const int wv = tid >> 6, lane = tid & 63;
  const int qsub = lane >> 2, c = lane & 3;
  const int ql = wv * 16 + qsub;
  const char* vpc = (const char*)vproj + c * 16;
  __half2 accA[4] = {}; // y0-row contributions
  __half2 accB[4] = {}; // y1-row contributions
#pragma unroll 4
  for (int lp = 0; lp < 16; lp++) {
#pragma unroll
    for (int yi = 0; yi < 2; yi++) {
      const u32x2 d = dpk[lp][yi][ql];
      const char* p = vpc + d[0];
      const u32x4 u0 = *(const u32x4*)p;
      const u32x4 u1 = *(const u32x4*)(p + 64);
      unsigned int dw = d[1];
      __half2 hw = *reinterpret_cast<__half2*>(&dw);
      __half2 w00 = __half2half2(__low2half(hw));
      __half2 w11 = __half2half2(__high2half(hw));
#pragma unroll
      for (int j = 0; j < 4; j++) {
        unsigned int t0 = u0[j], t1 = u1[j];
        __half2 v0 = *reinterpret_cast<__half2*>(&t0);
        __half2 v1 = *reinterpret_cast<__half2*>(&t1);
        accA[j] = __hfma2(v0, w00, accA[j]);
        accB[j] = __hfma2(v1, w11, accB[j]);
      }
    }
  }
  const int q = q0 + ql;
  if (q < NQ) {
    unsigned int up[4];
#pragma unroll
    for (int j = 0; j < 4; j++) {
      float2 fa = __half22float2(accA[j]);
      float2 fb = __half22float2(accB[j]);
      unsigned int b0 = (unsigned int)(unsigned short)bf16_of(fa.x + fb.x);
      unsigned int b1 = (unsigned int)(unsigned short)bf16_of(fa.y + fb.y);
      up[j] = (b1 << 16) | b0;
    }
    u32x4 pk = { up[0], up[1], up[2], up[3] };
    *(u32x4*)((unsigned short*)interm + ((size_t)b * NQ + q) * 256 + h * 32 + c * 8) = pk;
  }
}

extern "C" void kernel_launch(void* const* d_in, const int* in_sizes, int n_in,
                              void* d_out, int out_size, void* d_ws, size_t ws_size,
                              hipStream_t stream)
{
  const float* query = (const float*)d_in[0];
  const float* refp  = (const float*)d_in[1];
  const float* value = (const float*)d_in[2];
  // d_in[3] = spatial_shapes (static, hardcoded)
  const float* Wso = (const float*)d_in[4];
  const float* bso = (const float*)d_in[5];
  const float* Waw = (const float*)d_in[6];
  const float* baw = (const float*)d_in[7];
  const float* Wv  = (const float*)d_in[8];
  const float* bv  = (const float*)d_in[9];
  const float* Wo  = (const float*)d_in[10];
  const float* bo  = (const float*)d_in[11];

  char* ws = (char*)d_ws;
  __half* vproj          = (__half*)ws;                         // 13,613,056 B (fp16)
  __hip_bfloat16* offaw  = (__hip_bfloat16*)(ws + 13613056);    // 20,419,584 B
  __hip_bfloat16* interm = (__hip_bfloat16*)(ws + 34032640);    // 13,613,056 B
  short* WvT = (short*)(ws + 47645696);                         //    131,072 B
  short* WqT = (short*)(ws + 47776768);                         //    196,608 B
  short* WoT = (short*)(ws + 47973376);                         //    131,072 B
  float* bq  = (float*)(ws + 48104448);                         //      1,536 B
  float* out = (float*)d_out;

  dim3 blk(256);
  prep_k<<<dim3(57), blk, 0, stream>>>(Wv, Wso, Waw, Wo, bso, baw, WvT, WqT, WoT, bq);
  gemm01_k<<<dim3(832 + 1248), blk, 0, stream>>>(value, query, WvT, WqT, bv, bq, vproj, offaw);
  sample_k<<<dim3(16 * 208), blk, 0, stream>>>(vproj, offaw, refp, interm);
  gemm3_k<<<dim3(832), blk, 0, stream>>>((const short*)interm, WoT, bo, out);
}